// Round 6
// baseline (67.895 us; speedup 1.0000x reference)
//
#include <hip/hip_runtime.h>

#define NDIM 128   // feature dim D
#define NOUT 8     // output dim

typedef float f32x4 __attribute__((ext_vector_type(4)));

// Kernel 1 (v2): per-node projection, split-K x4.
// 4 threads per node, each does a 32-float quarter of the dot products,
// butterfly-reduced over the 4-lane group. 64 nodes/block -> 1563 blocks.
// P[n][0..7]  = h[n].Wu[o]        (src half)
// P[n][8..15] = h[n].Wv[o] + b[o] (dst half, bias baked in)
__global__ __launch_bounds__(256) void node_proj_kernel(
    const float* __restrict__ h, const float* __restrict__ W,
    const float* __restrict__ b, float* __restrict__ P, int n_nodes) {
  // LDS W: row o in [0,8) = Wu[o], row o in [8,16) = Wv[o-8]
  __shared__ f32x4 Wl[16][32];
  const int t = threadIdx.x;
  for (int i = t; i < 512; i += 256) {
    const int o = i >> 5;        // 0..15
    const int j = i & 31;        // 0..31
    const int row = o & 7;
    const int half = o >> 3;
    Wl[o][j] = reinterpret_cast<const f32x4*>(W + row * (2 * NDIM) + half * NDIM)[j];
  }
  __syncthreads();

  const int nl = t >> 2;         // node within block: 0..63
  const int kq = t & 3;          // K-quarter: 0..3
  const int n = blockIdx.x * 64 + nl;
  if (n >= n_nodes) return;

  // Load this thread's 32-float K-quarter of h[n] (8 x float4).
  const f32x4* __restrict__ hp =
      reinterpret_cast<const f32x4*>(h + (size_t)n * NDIM + kq * 32);
  f32x4 hv[8];
#pragma unroll
  for (int j = 0; j < 8; ++j) hv[j] = hp[j];

  float acc[16];
#pragma unroll
  for (int o = 0; o < 16; ++o) acc[o] = 0.0f;

#pragma unroll
  for (int j = 0; j < 8; ++j) {
    const f32x4 v = hv[j];
#pragma unroll
    for (int o = 0; o < 16; ++o) {
      const f32x4 w = Wl[o][kq * 8 + j];  // 4 distinct 16B addrs per wave: conflict-free
      acc[o] = fmaf(v.x, w.x,
               fmaf(v.y, w.y,
               fmaf(v.z, w.z,
               fmaf(v.w, w.w, acc[o]))));
    }
  }

  // Butterfly-reduce over the 4 lanes sharing this node (xor 1, xor 2).
#pragma unroll
  for (int o = 0; o < 16; ++o) acc[o] += __shfl_xor(acc[o], 1, 64);
#pragma unroll
  for (int o = 0; o < 16; ++o) acc[o] += __shfl_xor(acc[o], 2, 64);

  // Each lane writes its quarter of P[n][0..15]. Static indices only
  // (runtime-indexed acc would go to scratch).
  const f32x4* __restrict__ b4 = reinterpret_cast<const f32x4*>(b);
  f32x4 r;
  if (kq == 0) {
    r.x = acc[0];  r.y = acc[1];  r.z = acc[2];  r.w = acc[3];
  } else if (kq == 1) {
    r.x = acc[4];  r.y = acc[5];  r.z = acc[6];  r.w = acc[7];
  } else if (kq == 2) {
    const f32x4 bb = b4[0];
    r.x = acc[8] + bb.x;  r.y = acc[9] + bb.y;  r.z = acc[10] + bb.z;  r.w = acc[11] + bb.w;
  } else {
    const f32x4 bb = b4[1];
    r.x = acc[12] + bb.x; r.y = acc[13] + bb.y; r.z = acc[14] + bb.z;  r.w = acc[15] + bb.w;
  }
  // Wave writes 16 nodes x 64B = 1KB contiguous.
  reinterpret_cast<f32x4*>(P + (size_t)n * 16)[kq] = r;
}

// Kernel 2 (v2): per-edge gather + add, 2 edges/thread.
// Streaming traffic (indices in, scores out) is NONTEMPORAL so the 6.4MB
// P table keeps L2 residency; gathers stay cacheable.
__global__ __launch_bounds__(256) void edge_score_kernel(
    const int* __restrict__ src, const int* __restrict__ dst,
    const float* __restrict__ P, float* __restrict__ out, int n_edges) {
  const int t = threadIdx.x;
  const int e0 = blockIdx.x * 512 + t;
  const int e1 = e0 + 256;
  const bool v0 = e0 < n_edges;
  const bool v1 = e1 < n_edges;

  const f32x4* __restrict__ Pp = reinterpret_cast<const f32x4*>(P);
  f32x4* __restrict__ op = reinterpret_cast<f32x4*>(out);

  int s0 = 0, d0 = 0, s1 = 0, d1 = 0;
  if (v0) {
    s0 = __builtin_nontemporal_load(src + e0);
    d0 = __builtin_nontemporal_load(dst + e0);
  }
  if (v1) {
    s1 = __builtin_nontemporal_load(src + e1);
    d1 = __builtin_nontemporal_load(dst + e1);
  }

  if (v0) {
    const f32x4 sa = Pp[(size_t)s0 * 4 + 0];
    const f32x4 sb = Pp[(size_t)s0 * 4 + 1];
    const f32x4 da = Pp[(size_t)d0 * 4 + 2];
    const f32x4 db = Pp[(size_t)d0 * 4 + 3];
    __builtin_nontemporal_store(sa + da, op + (size_t)e0 * 2 + 0);
    __builtin_nontemporal_store(sb + db, op + (size_t)e0 * 2 + 1);
  }
  if (v1) {
    const f32x4 sa = Pp[(size_t)s1 * 4 + 0];
    const f32x4 sb = Pp[(size_t)s1 * 4 + 1];
    const f32x4 da = Pp[(size_t)d1 * 4 + 2];
    const f32x4 db = Pp[(size_t)d1 * 4 + 3];
    __builtin_nontemporal_store(sa + da, op + (size_t)e1 * 2 + 0);
    __builtin_nontemporal_store(sb + db, op + (size_t)e1 * 2 + 1);
  }
}

// Fallback (only if workspace is too small): direct per-edge computation.
__global__ __launch_bounds__(256) void edge_direct_kernel(
    const float* __restrict__ h, const int* __restrict__ src,
    const int* __restrict__ dst, const float* __restrict__ W,
    const float* __restrict__ b, float* __restrict__ out, int n_edges) {
  const int e = blockIdx.x * 256 + threadIdx.x;
  if (e >= n_edges) return;
  const int s = src[e];
  const int d = dst[e];
  const float4* __restrict__ hs = reinterpret_cast<const float4*>(h + (size_t)s * NDIM);
  const float4* __restrict__ hd = reinterpret_cast<const float4*>(h + (size_t)d * NDIM);
  const float4* __restrict__ W4 = reinterpret_cast<const float4*>(W);

  float acc[NOUT];
#pragma unroll
  for (int o = 0; o < NOUT; ++o) acc[o] = b[o];

  for (int j = 0; j < 32; ++j) {
    const float4 vs = hs[j];
    const float4 vd = hd[j];
#pragma unroll
    for (int o = 0; o < NOUT; ++o) {
      const float4 wu = W4[o * 64 + j];
      const float4 wv = W4[o * 64 + 32 + j];
      acc[o] = fmaf(vs.x, wu.x, fmaf(vs.y, wu.y, fmaf(vs.z, wu.z, fmaf(vs.w, wu.w, acc[o]))));
      acc[o] = fmaf(vd.x, wv.x, fmaf(vd.y, wv.y, fmaf(vd.z, wv.z, fmaf(vd.w, wv.w, acc[o]))));
    }
  }

  float4 r0, r1;
  r0.x = acc[0]; r0.y = acc[1]; r0.z = acc[2]; r0.w = acc[3];
  r1.x = acc[4]; r1.y = acc[5]; r1.z = acc[6]; r1.w = acc[7];
  float4* __restrict__ op = reinterpret_cast<float4*>(out + (size_t)e * NOUT);
  op[0] = r0;
  op[1] = r1;
}

extern "C" void kernel_launch(void* const* d_in, const int* in_sizes, int n_in,
                              void* d_out, int out_size, void* d_ws, size_t ws_size,
                              hipStream_t stream) {
  const float* h   = (const float*)d_in[0];
  const int*   src = (const int*)d_in[1];
  const int*   dst = (const int*)d_in[2];
  const float* W   = (const float*)d_in[3];
  const float* b   = (const float*)d_in[4];
  float* out = (float*)d_out;

  const int n_nodes = in_sizes[0] / NDIM;
  const int n_edges = in_sizes[1];

  const size_t need = (size_t)n_nodes * 16 * sizeof(float);
  if (ws_size >= need) {
    float* P = (float*)d_ws;
    node_proj_kernel<<<(n_nodes + 63) / 64, 256, 0, stream>>>(h, W, b, P, n_nodes);
    edge_score_kernel<<<(n_edges + 511) / 512, 256, 0, stream>>>(src, dst, P, out, n_edges);
  } else {
    edge_direct_kernel<<<(n_edges + 255) / 256, 256, 0, stream>>>(h, src, dst, W, b, out, n_edges);
  }
}

// Round 7
// 66.696 us; speedup vs baseline: 1.0180x; 1.0180x over previous
//
#include <hip/hip_runtime.h>

#define NDIM 128   // feature dim D
#define NOUT 8     // output dim

typedef float     f32x4 __attribute__((ext_vector_type(4)));
typedef _Float16  f16x4 __attribute__((ext_vector_type(4)));
typedef _Float16  f16x8 __attribute__((ext_vector_type(8)));

// Kernel 1 (v3): per-node projection, NO LDS in main loop.
// Block = 256 = 4 waves, 64 nodes/block. Wave w handles K-quarter w
// (wave-uniform -> W reads become s_load from K$, off the vector path).
// Cross-wave reduce via 16KB LDS at the end. P is fp16 [n][16]:
//   P[n][0..7]  = h[n].Wu[o]          (src half)
//   P[n][8..15] = h[n].Wv[o] + b[o]   (dst half, bias baked in)
__global__ __launch_bounds__(256) void node_proj_kernel(
    const float* __restrict__ h, const float* __restrict__ W,
    const float* __restrict__ b, _Float16* __restrict__ P, int n_nodes) {
  __shared__ float red[4][16][64];   // [wave(kq)][out][node-lane]
  const int t = threadIdx.x;
  const int l = t & 63;              // node within block
  const int w = t >> 6;              // wave id = K-quarter
  const int kq = __builtin_amdgcn_readfirstlane(w);  // force SGPR (uniform)

  const int n = blockIdx.x * 64 + l;
  const bool valid = (n < n_nodes);

  // This wave's 32-float K-slice of h[n] (8 x float4, L1-friendly).
  f32x4 hv[8];
  if (valid) {
    const f32x4* __restrict__ hp =
        reinterpret_cast<const f32x4*>(h + (size_t)n * NDIM + kq * 32);
#pragma unroll
    for (int j = 0; j < 8; ++j) hv[j] = hp[j];
  } else {
#pragma unroll
    for (int j = 0; j < 8; ++j) hv[j] = f32x4{0.f, 0.f, 0.f, 0.f};
  }

  const float* __restrict__ Wq = W + kq * 32;  // uniform base

  float acc[16];
#pragma unroll
  for (int o = 0; o < 16; ++o) acc[o] = 0.f;

#pragma unroll
  for (int o = 0; o < 16; ++o) {
    const int row = o & 7;
    const int half = o >> 3;           // 0 = Wu, 1 = Wv
    // 32 contiguous floats, wave-uniform address -> s_load_dwordx*
    const float* __restrict__ wrow = Wq + row * (2 * NDIM) + half * NDIM;
#pragma unroll
    for (int j = 0; j < 8; ++j) {
      const f32x4 v = hv[j];
      acc[o] = fmaf(v.x, wrow[j * 4 + 0],
               fmaf(v.y, wrow[j * 4 + 1],
               fmaf(v.z, wrow[j * 4 + 2],
               fmaf(v.w, wrow[j * 4 + 3], acc[o]))));
    }
  }

  // Stage partials: red[w][o][l] -> lane-consecutive dwords, conflict-free.
#pragma unroll
  for (int o = 0; o < 16; ++o) red[w][o][l] = acc[o];
  __syncthreads();

  // Reduce: thread t handles node nl = t>>2, output-quarter q = t&3.
  const int nl = t >> 2;
  const int q = t & 3;
  const int n2 = blockIdx.x * 64 + nl;
  if (n2 < n_nodes) {
    float s0 = 0.f, s1 = 0.f, s2 = 0.f, s3 = 0.f;
#pragma unroll
    for (int ww = 0; ww < 4; ++ww) {
      s0 += red[ww][q * 4 + 0][nl];
      s1 += red[ww][q * 4 + 1][nl];
      s2 += red[ww][q * 4 + 2][nl];
      s3 += red[ww][q * 4 + 3][nl];
    }
    if (q >= 2) {  // dst half: bake bias in
      const f32x4 bb = reinterpret_cast<const f32x4*>(b)[q - 2];
      s0 += bb.x; s1 += bb.y; s2 += bb.z; s3 += bb.w;
    }
    f16x4 r;
    r[0] = (_Float16)s0; r[1] = (_Float16)s1;
    r[2] = (_Float16)s2; r[3] = (_Float16)s3;
    // 4 lanes x 8B cover the node's 32B row -> coalesced.
    reinterpret_cast<f16x4*>(P + (size_t)n2 * 16)[q] = r;
  }
}

// Kernel 2 (v3): per-edge gather + add from the fp16 P table (3.2MB,
// fits per-XCD L2). 2 x 16B gathers per edge (was 4). Streaming traffic
// (indices in, scores out) stays nontemporal to protect P residency.
__global__ __launch_bounds__(256) void edge_score_kernel(
    const int* __restrict__ src, const int* __restrict__ dst,
    const _Float16* __restrict__ P, float* __restrict__ out, int n_edges) {
  const int t = threadIdx.x;
  const int e0 = blockIdx.x * 512 + t;
  const int e1 = e0 + 256;
  const bool v0 = e0 < n_edges;
  const bool v1 = e1 < n_edges;

  const f16x8* __restrict__ Pp = reinterpret_cast<const f16x8*>(P);
  f32x4* __restrict__ op = reinterpret_cast<f32x4*>(out);

  int s0 = 0, d0 = 0, s1 = 0, d1 = 0;
  if (v0) {
    s0 = __builtin_nontemporal_load(src + e0);
    d0 = __builtin_nontemporal_load(dst + e0);
  }
  if (v1) {
    s1 = __builtin_nontemporal_load(src + e1);
    d1 = __builtin_nontemporal_load(dst + e1);
  }

  if (v0) {
    const f16x8 sv = Pp[(size_t)s0 * 2 + 0];   // src half of node s0
    const f16x8 dv = Pp[(size_t)d0 * 2 + 1];   // dst half of node d0
    f32x4 r0, r1;
    r0.x = (float)sv[0] + (float)dv[0]; r0.y = (float)sv[1] + (float)dv[1];
    r0.z = (float)sv[2] + (float)dv[2]; r0.w = (float)sv[3] + (float)dv[3];
    r1.x = (float)sv[4] + (float)dv[4]; r1.y = (float)sv[5] + (float)dv[5];
    r1.z = (float)sv[6] + (float)dv[6]; r1.w = (float)sv[7] + (float)dv[7];
    __builtin_nontemporal_store(r0, op + (size_t)e0 * 2 + 0);
    __builtin_nontemporal_store(r1, op + (size_t)e0 * 2 + 1);
  }
  if (v1) {
    const f16x8 sv = Pp[(size_t)s1 * 2 + 0];
    const f16x8 dv = Pp[(size_t)d1 * 2 + 1];
    f32x4 r0, r1;
    r0.x = (float)sv[0] + (float)dv[0]; r0.y = (float)sv[1] + (float)dv[1];
    r0.z = (float)sv[2] + (float)dv[2]; r0.w = (float)sv[3] + (float)dv[3];
    r1.x = (float)sv[4] + (float)dv[4]; r1.y = (float)sv[5] + (float)dv[5];
    r1.z = (float)sv[6] + (float)dv[6]; r1.w = (float)sv[7] + (float)dv[7];
    __builtin_nontemporal_store(r0, op + (size_t)e1 * 2 + 0);
    __builtin_nontemporal_store(r1, op + (size_t)e1 * 2 + 1);
  }
}

// Fallback (only if workspace is too small): direct per-edge computation.
__global__ __launch_bounds__(256) void edge_direct_kernel(
    const float* __restrict__ h, const int* __restrict__ src,
    const int* __restrict__ dst, const float* __restrict__ W,
    const float* __restrict__ b, float* __restrict__ out, int n_edges) {
  const int e = blockIdx.x * 256 + threadIdx.x;
  if (e >= n_edges) return;
  const int s = src[e];
  const int d = dst[e];
  const float4* __restrict__ hs = reinterpret_cast<const float4*>(h + (size_t)s * NDIM);
  const float4* __restrict__ hd = reinterpret_cast<const float4*>(h + (size_t)d * NDIM);
  const float4* __restrict__ W4 = reinterpret_cast<const float4*>(W);

  float acc[NOUT];
#pragma unroll
  for (int o = 0; o < NOUT; ++o) acc[o] = b[o];

  for (int j = 0; j < 32; ++j) {
    const float4 vs = hs[j];
    const float4 vd = hd[j];
#pragma unroll
    for (int o = 0; o < NOUT; ++o) {
      const float4 wu = W4[o * 64 + j];
      const float4 wv = W4[o * 64 + 32 + j];
      acc[o] = fmaf(vs.x, wu.x, fmaf(vs.y, wu.y, fmaf(vs.z, wu.z, fmaf(vs.w, wu.w, acc[o]))));
      acc[o] = fmaf(vd.x, wv.x, fmaf(vd.y, wv.y, fmaf(vd.z, wv.z, fmaf(vd.w, wv.w, acc[o]))));
    }
  }

  float4 r0, r1;
  r0.x = acc[0]; r0.y = acc[1]; r0.z = acc[2]; r0.w = acc[3];
  r1.x = acc[4]; r1.y = acc[5]; r1.z = acc[6]; r1.w = acc[7];
  float4* __restrict__ op = reinterpret_cast<float4*>(out + (size_t)e * NOUT);
  op[0] = r0;
  op[1] = r1;
}

extern "C" void kernel_launch(void* const* d_in, const int* in_sizes, int n_in,
                              void* d_out, int out_size, void* d_ws, size_t ws_size,
                              hipStream_t stream) {
  const float* h   = (const float*)d_in[0];
  const int*   src = (const int*)d_in[1];
  const int*   dst = (const int*)d_in[2];
  const float* W   = (const float*)d_in[3];
  const float* b   = (const float*)d_in[4];
  float* out = (float*)d_out;

  const int n_nodes = in_sizes[0] / NDIM;
  const int n_edges = in_sizes[1];

  const size_t need = (size_t)n_nodes * 16 * sizeof(_Float16);  // 3.2 MB
  if (ws_size >= need) {
    _Float16* P = (_Float16*)d_ws;
    node_proj_kernel<<<(n_nodes + 63) / 64, 256, 0, stream>>>(h, W, b, P, n_nodes);
    edge_score_kernel<<<(n_edges + 511) / 512, 256, 0, stream>>>(src, dst, P, out, n_edges);
  } else {
    edge_direct_kernel<<<(n_edges + 255) / 256, 256, 0, stream>>>(h, src, dst, W, b, out, n_edges);
  }
}

// Round 8
// 47.384 us; speedup vs baseline: 1.4329x; 1.4076x over previous
//
#include <hip/hip_runtime.h>

#define NDIM 128   // feature dim D
#define NOUT 8     // output dim

typedef float     f32x4 __attribute__((ext_vector_type(4)));
typedef _Float16  f16x8 __attribute__((ext_vector_type(8)));

// Kernel 1 (v4): per-node projection via MFMA.
// One wave computes a 16-node x 16-output tile: D = A(16x128) x B(128x16)
// as 4 x mfma_f32_16x16x32_f16, f32 accumulate. No LDS.
//   P[n][0..7]  = h[n].Wu[o]          (src half)
//   P[n][8..15] = h[n].Wv[o] + b[o]   (dst half, bias baked in)
// Layouts (gfx950 16x16x32): A: row=lane&15, k=(lane>>4)*8+j (8 contiguous);
// B: col=lane&15, same k slice; D: col=lane&15, row=(lane>>4)*4+reg.
__global__ __launch_bounds__(256) void node_proj_kernel(
    const float* __restrict__ h, const float* __restrict__ W,
    const float* __restrict__ b, _Float16* __restrict__ P, int n_nodes) {
  const int lane = threadIdx.x & 63;
  const int wv   = threadIdx.x >> 6;           // wave id in block (0..3)
  const int nb   = blockIdx.x * 64 + wv * 16;  // this wave's base node
  const int c    = lane & 15;                  // A-row / B-col / D-col
  const int kg   = lane >> 4;                  // k-group (0..3)

  // B fragments: W'[col=c][k], combined row c: c<8 -> Wu[c], c>=8 -> Wv[c-8].
  // W is [8][256] with Wu = cols 0..127, Wv = cols 128..255.
  const float* __restrict__ wp =
      W + (c & 7) * (2 * NDIM) + (c >> 3) * NDIM + kg * 8;
  f16x8 bf[4];
#pragma unroll
  for (int s = 0; s < 4; ++s) {
    const f32x4 w0 = *reinterpret_cast<const f32x4*>(wp + s * 32);
    const f32x4 w1 = *reinterpret_cast<const f32x4*>(wp + s * 32 + 4);
    f16x8 t;
    t[0] = (_Float16)w0.x; t[1] = (_Float16)w0.y;
    t[2] = (_Float16)w0.z; t[3] = (_Float16)w0.w;
    t[4] = (_Float16)w1.x; t[5] = (_Float16)w1.y;
    t[6] = (_Float16)w1.z; t[7] = (_Float16)w1.w;
    bf[s] = t;
  }

  // A fragments: h[node=nb+c][k], k = s*32 + kg*8 .. +8 (f32 -> f16).
  const int node = nb + c;
  const bool valid = node < n_nodes;
  const float* __restrict__ hp = h + (size_t)node * NDIM + kg * 8;

  f32x4 acc = {0.f, 0.f, 0.f, 0.f};
#pragma unroll
  for (int s = 0; s < 4; ++s) {
    f16x8 af = {};
    if (valid) {
      const f32x4 a0 = *reinterpret_cast<const f32x4*>(hp + s * 32);
      const f32x4 a1 = *reinterpret_cast<const f32x4*>(hp + s * 32 + 4);
      af[0] = (_Float16)a0.x; af[1] = (_Float16)a0.y;
      af[2] = (_Float16)a0.z; af[3] = (_Float16)a0.w;
      af[4] = (_Float16)a1.x; af[5] = (_Float16)a1.y;
      af[6] = (_Float16)a1.z; af[7] = (_Float16)a1.w;
    }
    acc = __builtin_amdgcn_mfma_f32_16x16x32_f16(af, bf[s], acc, 0, 0, 0);
  }

  // Epilogue: lane writes D rows kg*4..kg*4+3, col c. Bias on dst half.
  const float bias = (c >= 8) ? b[c - 8] : 0.f;
#pragma unroll
  for (int i = 0; i < 4; ++i) {
    const int nrow = nb + kg * 4 + i;
    if (nrow < n_nodes)
      P[(size_t)nrow * 16 + c] = (_Float16)(acc[i] + bias);
  }
}

// Kernel 2 (v3, unchanged): per-edge gather + add from the fp16 P table
// (3.2MB, fits per-XCD L2). 2 x 16B gathers per edge. Streaming traffic
// (indices in, scores out) is nontemporal to protect P residency.
__global__ __launch_bounds__(256) void edge_score_kernel(
    const int* __restrict__ src, const int* __restrict__ dst,
    const _Float16* __restrict__ P, float* __restrict__ out, int n_edges) {
  const int t = threadIdx.x;
  const int e0 = blockIdx.x * 512 + t;
  const int e1 = e0 + 256;
  const bool v0 = e0 < n_edges;
  const bool v1 = e1 < n_edges;

  const f16x8* __restrict__ Pp = reinterpret_cast<const f16x8*>(P);
  f32x4* __restrict__ op = reinterpret_cast<f32x4*>(out);

  int s0 = 0, d0 = 0, s1 = 0, d1 = 0;
  if (v0) {
    s0 = __builtin_nontemporal_load(src + e0);
    d0 = __builtin_nontemporal_load(dst + e0);
  }
  if (v1) {
    s1 = __builtin_nontemporal_load(src + e1);
    d1 = __builtin_nontemporal_load(dst + e1);
  }

  if (v0) {
    const f16x8 sv = Pp[(size_t)s0 * 2 + 0];   // src half of node s0
    const f16x8 dv = Pp[(size_t)d0 * 2 + 1];   // dst half of node d0
    f32x4 r0, r1;
    r0.x = (float)sv[0] + (float)dv[0]; r0.y = (float)sv[1] + (float)dv[1];
    r0.z = (float)sv[2] + (float)dv[2]; r0.w = (float)sv[3] + (float)dv[3];
    r1.x = (float)sv[4] + (float)dv[4]; r1.y = (float)sv[5] + (float)dv[5];
    r1.z = (float)sv[6] + (float)dv[6]; r1.w = (float)sv[7] + (float)dv[7];
    __builtin_nontemporal_store(r0, op + (size_t)e0 * 2 + 0);
    __builtin_nontemporal_store(r1, op + (size_t)e0 * 2 + 1);
  }
  if (v1) {
    const f16x8 sv = Pp[(size_t)s1 * 2 + 0];
    const f16x8 dv = Pp[(size_t)d1 * 2 + 1];
    f32x4 r0, r1;
    r0.x = (float)sv[0] + (float)dv[0]; r0.y = (float)sv[1] + (float)dv[1];
    r0.z = (float)sv[2] + (float)dv[2]; r0.w = (float)sv[3] + (float)dv[3];
    r1.x = (float)sv[4] + (float)dv[4]; r1.y = (float)sv[5] + (float)dv[5];
    r1.z = (float)sv[6] + (float)dv[6]; r1.w = (float)sv[7] + (float)dv[7];
    __builtin_nontemporal_store(r0, op + (size_t)e1 * 2 + 0);
    __builtin_nontemporal_store(r1, op + (size_t)e1 * 2 + 1);
  }
}

// Fallback (only if workspace is too small): direct per-edge computation.
__global__ __launch_bounds__(256) void edge_direct_kernel(
    const float* __restrict__ h, const int* __restrict__ src,
    const int* __restrict__ dst, const float* __restrict__ W,
    const float* __restrict__ b, float* __restrict__ out, int n_edges) {
  const int e = blockIdx.x * 256 + threadIdx.x;
  if (e >= n_edges) return;
  const int s = src[e];
  const int d = dst[e];
  const float4* __restrict__ hs = reinterpret_cast<const float4*>(h + (size_t)s * NDIM);
  const float4* __restrict__ hd = reinterpret_cast<const float4*>(h + (size_t)d * NDIM);
  const float4* __restrict__ W4 = reinterpret_cast<const float4*>(W);

  float acc[NOUT];
#pragma unroll
  for (int o = 0; o < NOUT; ++o) acc[o] = b[o];

  for (int j = 0; j < 32; ++j) {
    const float4 vs = hs[j];
    const float4 vd = hd[j];
#pragma unroll
    for (int o = 0; o < NOUT; ++o) {
      const float4 wu = W4[o * 64 + j];
      const float4 wv = W4[o * 64 + 32 + j];
      acc[o] = fmaf(vs.x, wu.x, fmaf(vs.y, wu.y, fmaf(vs.z, wu.z, fmaf(vs.w, wu.w, acc[o]))));
      acc[o] = fmaf(vd.x, wv.x, fmaf(vd.y, wv.y, fmaf(vd.z, wv.z, fmaf(vd.w, wv.w, acc[o]))));
    }
  }

  float4 r0, r1;
  r0.x = acc[0]; r0.y = acc[1]; r0.z = acc[2]; r0.w = acc[3];
  r1.x = acc[4]; r1.y = acc[5]; r1.z = acc[6]; r1.w = acc[7];
  float4* __restrict__ op = reinterpret_cast<float4*>(out + (size_t)e * NOUT);
  op[0] = r0;
  op[1] = r1;
}

extern "C" void kernel_launch(void* const* d_in, const int* in_sizes, int n_in,
                              void* d_out, int out_size, void* d_ws, size_t ws_size,
                              hipStream_t stream) {
  const float* h   = (const float*)d_in[0];
  const int*   src = (const int*)d_in[1];
  const int*   dst = (const int*)d_in[2];
  const float* W   = (const float*)d_in[3];
  const float* b   = (const float*)d_in[4];
  float* out = (float*)d_out;

  const int n_nodes = in_sizes[0] / NDIM;
  const int n_edges = in_sizes[1];

  const size_t need = (size_t)n_nodes * 16 * sizeof(_Float16);  // 3.2 MB
  if (ws_size >= need) {
    _Float16* P = (_Float16*)d_ws;
    node_proj_kernel<<<(n_nodes + 63) / 64, 256, 0, stream>>>(h, W, b, P, n_nodes);
    edge_score_kernel<<<(n_edges + 511) / 512, 256, 0, stream>>>(src, dst, P, out, n_edges);
  } else {
    edge_direct_kernel<<<(n_edges + 255) / 256, 256, 0, stream>>>(h, src, dst, W, b, out, n_edges);
  }
}